// Round 1
// baseline (688.723 us; speedup 1.0000x reference)
//
#include <hip/hip_runtime.h>

#define BB 4096
#define CC 32000
#define CPAD 32768             // padded column count (zeros beyond CC)
#define NT 1024                // threads per block = 16 waves
#define NI 8                   // float4 chunks per thread: NT*4*NI = CPAD
#define GRID 256               // one block per CU
#define RPB (BB / GRID)        // 16 rows per block
#define NW (NT / 64)           // 16 waves
#define FBLK (CPAD / 4 / 256)  // 32 finalize blocks: exactly CPAD/4 quads

typedef float v4f __attribute__((ext_vector_type(4)));

// Single pass over x: per row exp -> Z -> scale, accumulate confidence sums in
// REGISTERS (thread t owns the same 32 columns for every row -> no LDS acc, no
// 128KB LDS footprint, occupancy 2 waves/SIMD -> 4 waves/SIMD).
__global__ __launch_bounds__(NT, 4) void mdca_main(const float* __restrict__ x,
                                                   const int* __restrict__ tgt,
                                                   float* __restrict__ partial,
                                                   float* __restrict__ counts) {
    __shared__ float red[2][NW];  // double-buffered per-wave Z partials -> 1 barrier/row

    const int t = threadIdx.x;
    const int wid = t >> 6;
    const int r0 = blockIdx.x * RPB;

    // chunk NI-1 covers cols [28672, 32768); valid iff 4t < CC-28672=3328 -> t<832.
    // 832 = 13*64: the guard is wave-uniform (waves 13..15 idle on chunk 7).
    const bool tail_ok = ((NI - 1) * (NT * 4) + 4 * t) < CC;

    v4f cur[NI], nxt[NI], acc[NI];
#pragma unroll
    for (int i = 0; i < NI; ++i) acc[i] = (v4f){0.f, 0.f, 0.f, 0.f};

    // preload row r0 (thread t owns cols i*4096 + 4t .. +3)
    {
        const float* rp = x + (size_t)r0 * CC;
#pragma unroll
        for (int i = 0; i < NI; ++i) {
            const int col = i * (NT * 4) + 4 * t;
            if (i < NI - 1 || tail_ok) cur[i] = *(const v4f*)(rp + col);
        }
    }

    for (int r = 0; r < RPB; ++r) {
        const int p = r & 1;
        // issue next row's loads FIRST: they stay in flight through exp/reduce
        // and are drained by the compiler's vmcnt(0) at the barrier below.
        if (r + 1 < RPB) {
            const float* rq = x + (size_t)(r0 + r + 1) * CC;
#pragma unroll
            for (int i = 0; i < NI; ++i) {
                const int col = i * (NT * 4) + 4 * t;
                if (i < NI - 1 || tail_ok) nxt[i] = *(const v4f*)(rq + col);
            }
        }
        // exp current row in-register; per-thread partial sum
        float s = 0.f;
#pragma unroll
        for (int i = 0; i < NI; ++i) {
            if (i < NI - 1 || tail_ok) {
                v4f e;
                e.x = __expf(cur[i].x); e.y = __expf(cur[i].y);
                e.z = __expf(cur[i].z); e.w = __expf(cur[i].w);
                cur[i] = e;
                s += e.x + e.y + e.z + e.w;
            }
        }
        // wave reduce -> per-wave partial in LDS
        for (int off = 32; off > 0; off >>= 1) s += __shfl_down(s, off);
        if ((t & 63) == 0) red[p][wid] = s;
        __syncthreads();
        // every thread sums the 16 wave partials itself (broadcast reads; kills
        // the serial thread-0 section and the second barrier). Buffer parity p
        // makes the next row's red writes race-free with this row's reads.
        float z = 0.f;
#pragma unroll
        for (int w = 0; w < NW; ++w) z += red[p][w];
        const float rz = 1.0f / z;
        // scale-accumulate into registers
#pragma unroll
        for (int i = 0; i < NI; ++i) {
            if (i < NI - 1 || tail_ok) {
                acc[i].x += cur[i].x * rz; acc[i].y += cur[i].y * rz;
                acc[i].z += cur[i].z * rz; acc[i].w += cur[i].w * rz;
            }
        }
        if (r + 1 < RPB) {
#pragma unroll
            for (int i = 0; i < NI; ++i) cur[i] = nxt[i];
        }
    }

    // write this block's column partials (acc[NI-1] is still zero for tail-idle
    // threads, so the pad region [CC, CPAD) is written as zeros)
    v4f* pp = (v4f*)(partial + (size_t)blockIdx.x * CPAD);
#pragma unroll
    for (int i = 0; i < NI; ++i) pp[i * NT + t] = acc[i];

    // fused bincount: one atomic per row
    if (t < RPB) atomicAdd(&counts[tgt[r0 + t]], 1.0f);
}

// loss = (1/(B*C)) * sum_c | sum_b partial[b][c] - counts[c] |
__global__ __launch_bounds__(256) void finalize(const float* __restrict__ partial,
                                                const float* __restrict__ counts,
                                                float* __restrict__ total,
                                                unsigned* __restrict__ blkcnt,
                                                float* __restrict__ out) {
    const int g = blockIdx.x * 256 + threadIdx.x;  // quad index, < CPAD/4 exactly
    v4f s = {0.f, 0.f, 0.f, 0.f};
    const v4f* pv = (const v4f*)partial;
#pragma unroll 4
    for (int b = 0; b < GRID; ++b) {
        v4f p = pv[(size_t)b * (CPAD / 4) + g];
        s.x += p.x; s.y += p.y; s.z += p.z; s.w += p.w;
    }
    float v = 0.f;
    const int c = 4 * g;
    if (c < CC) {  // CC % 4 == 0, so c+3 < CC too; pad quads contribute 0
        v4f cnt = *(const v4f*)(counts + c);
        v = fabsf(s.x - cnt.x) + fabsf(s.y - cnt.y) + fabsf(s.z - cnt.z) + fabsf(s.w - cnt.w);
    }
    for (int off = 32; off > 0; off >>= 1) v += __shfl_down(v, off);
    __shared__ float wsum[4];
    if ((threadIdx.x & 63) == 0) wsum[threadIdx.x >> 6] = v;
    __syncthreads();
    if (threadIdx.x == 0) {
        atomicAdd(total, wsum[0] + wsum[1] + wsum[2] + wsum[3]);
        __threadfence();
        unsigned prev = atomicAdd(blkcnt, 1u);
        if (prev == FBLK - 1) {
            float tot = atomicAdd(total, 0.0f);  // device-scope read of final value
            out[0] = tot * (1.0f / ((float)BB * (float)CC));
        }
    }
}

extern "C" void kernel_launch(void* const* d_in, const int* in_sizes, int n_in,
                              void* d_out, int out_size, void* d_ws, size_t ws_size,
                              hipStream_t stream) {
    const float* x = (const float*)d_in[0];
    const int* tgt = (const int*)d_in[1];
    float* out = (float*)d_out;

    // ws layout (floats): partial[GRID*CPAD] | counts[CC] | total | blkcnt
    float* partial = (float*)d_ws;  // 33,554,432 B
    float* counts = partial + (size_t)GRID * CPAD;
    float* total = counts + CC;
    unsigned* blkcnt = (unsigned*)(total + 1);

    (void)hipMemsetAsync(counts, 0, (size_t)(CC + 2) * 4, stream);

    mdca_main<<<GRID, NT, 0, stream>>>(x, tgt, partial, counts);
    finalize<<<FBLK, 256, 0, stream>>>(partial, counts, total, blkcnt, out);
}